// Round 1
// 207.451 us; speedup vs baseline: 1.0596x; 1.0596x over previous
//
#include <hip/hip_runtime.h>
#include <hip/hip_fp16.h>

#define NN 50000
#define NE 800000
#define NF (NN * 64)
#define CAP 64                  // ELL capacity; deg ~ Poisson(16), P(deg>64) ~ 0
#define NH 3                    // fp16 apps; + 1 extrapolating fp32 finisher

typedef unsigned uv2 __attribute__((ext_vector_type(2)));
typedef unsigned uv4 __attribute__((ext_vector_type(4)));

static __device__ __forceinline__ float2 uph(unsigned u) {
    __half2 h = *(reinterpret_cast<__half2*>(&u));
    return __half22float2(h);
}
static __device__ __forceinline__ unsigned pkh(float a, float b) {
    __half2 h = __floats2half2_rn(a, b);
    return *(reinterpret_cast<unsigned*>(&h));
}
// pack (src:16 | fp16 weight:16); weight is positive (raw e in [0,1))
static __device__ __forceinline__ unsigned pack_sw(unsigned s, float w) {
    return ((unsigned)__half_as_ushort(__float2half_rn(w)) << 16) | s;
}
static __device__ __forceinline__ float unpack_w(unsigned u) {
    return __half2float(__ushort_as_half((unsigned short)(u >> 16)));
}

// ---------------- build ----------------

// fused: blocks [0, CVTB) cast b fp32->fp16 (streaming); blocks [CVTB, ...)
// zero the per-node counters.
#define CVTB (NF / 4 / 256)          // 3125 (exact)
#define ZB ((NN + 255) / 256)        // 196
__global__ __launch_bounds__(256) void zero_cvt(int* __restrict__ cnt,
                                                const float4* __restrict__ b4,
                                                uv2* __restrict__ bh) {
    if (blockIdx.x < CVTB) {
        int i = blockIdx.x * 256 + threadIdx.x;
        float4 v = b4[i];
        uv2 r;
        r.x = pkh(v.x, v.y);
        r.y = pkh(v.z, v.w);
        bh[i] = r;
    } else {
        int i = (blockIdx.x - CVTB) * 256 + threadIdx.x;
        if (i < NN) cnt[i] = 0;
    }
}

// single-pass ELL build with RAW fp16 weights (normalization happens on the
// fly in the gathers). Bounce-bound floor ~46us; r5/r11 locality variants
// both failed to beat this, coop-fusion (r14) was 6x worse.
__global__ __launch_bounds__(256) void build_ell(const float* __restrict__ e,
                                                 const int* __restrict__ src,
                                                 const int* __restrict__ dst,
                                                 int* __restrict__ cnt,
                                                 unsigned* __restrict__ ell) {
    int i = blockIdx.x * 256 + threadIdx.x;
    if (i < NE) {
        int d = dst[i];
        int r = atomicAdd(&cnt[d], 1);
        if (r < CAP)
            ell[d * CAP + r] = pack_sw((unsigned)src[i], e[i]);
    }
}

// ---------------- hot loop ----------------
// One wave per node. 8 edge-groups (g) x 8 feature-lanes (fl); fp16 row =
// 128B = 8 lanes x 16B (uv4).
//
// MLP restructure (this round): the old loop was
//   load ell[j] -> wait -> load xh[src] -> wait -> fma   (per-wave MLP ~ 1)
// which Little's-law-limits the whole dispatch to ~2.8 TB/s of random
// L2/L3 traffic (matches the observed ~38us/gather). Now: the ELL row is
// exactly CAP=64 words, so one wave-wide coalesced load (256B) pulls the
// whole row into registers; edge words are distributed to groups via
// ds_bpermute (__shfl, ~64cy instead of a 600-900cy VMEM round trip), and
// the edge loop is unrolled 4-wide with predicated tails so 4 independent
// xh row-gathers are in flight per wave. FP accumulation order per group
// is unchanged (ascending j), so numerics are identical.

static __device__ __forceinline__ void acc8(float w, uv4 u,
                                            float* __restrict__ a, float& ws) {
    float2 f;
    f = uph(u.x); a[0] += w * f.x; a[1] += w * f.y;
    f = uph(u.y); a[2] += w * f.x; a[3] += w * f.y;
    f = uph(u.z); a[4] += w * f.x; a[5] += w * f.y;
    f = uph(u.w); a[6] += w * f.x; a[7] += w * f.y;
    ws += w;
}

static __device__ __forceinline__ void gather_core(
        const uv4* __restrict__ xh, const int* __restrict__ cnt,
        const unsigned* __restrict__ ell, int wid, int lane,
        float* __restrict__ a, float& ws) {
    int g = lane >> 3;    // edge group 0..7
    int fl = lane & 7;    // 16B chunk within the 128B row
    // two independent loads in flight immediately
    int deg = cnt[wid];
    unsigned myp = ell[(long)wid * CAP + lane];   // whole ELL row, 1 coalesced load
    deg = deg < CAP ? deg : CAP;
#pragma unroll
    for (int k = 0; k < 8; ++k) a[k] = 0.0f;
    ws = 0.0f;
    int T = (deg + 7) >> 3;           // wave-uniform trip count, T <= 8
    for (int t = 0; t < T; t += 4) {  // at most 2 iterations; 1 for deg<=32 (98%)
        int jb = (t << 3) + g;
        // distribute edge words from the register-resident row (ds_bpermute)
        unsigned p0 = __shfl(myp, jb);
        unsigned p1 = __shfl(myp, jb + 8);
        unsigned p2 = __shfl(myp, jb + 16);
        unsigned p3 = __shfl(myp, jb + 24);
        bool v0 = jb      < deg;
        bool v1 = jb + 8  < deg;
        bool v2 = jb + 16 < deg;
        bool v3 = jb + 24 < deg;
        float w0 = v0 ? unpack_w(p0) : 0.0f;
        float w1 = v1 ? unpack_w(p1) : 0.0f;
        float w2 = v2 ? unpack_w(p2) : 0.0f;
        float w3 = v3 ? unpack_w(p3) : 0.0f;
        int s0 = v0 ? (int)(p0 & 0xFFFFu) : 0;   // clamp: safe dummy row, w=0
        int s1 = v1 ? (int)(p1 & 0xFFFFu) : 0;
        int s2 = v2 ? (int)(p2 & 0xFFFFu) : 0;
        int s3 = v3 ? (int)(p3 & 0xFFFFu) : 0;
        // 4 independent row-gathers in flight (the whole point)
        uv4 u0 = xh[s0 * 8 + fl];
        uv4 u1 = xh[s1 * 8 + fl];
        uv4 u2 = xh[s2 * 8 + fl];
        uv4 u3 = xh[s3 * 8 + fl];
        acc8(w0, u0, a, ws);
        acc8(w1, u1, a, ws);
        acc8(w2, u2, a, ws);
        acc8(w3, u3, a, ws);
    }
#pragma unroll
    for (int m = 8; m <= 32; m <<= 1) {
#pragma unroll
        for (int k = 0; k < 8; ++k) a[k] += __shfl_xor(a[k], m);
        ws += __shfl_xor(ws, m);
    }
}

__global__ __launch_bounds__(256) void gather_h(const uv4* __restrict__ xh,
                                                const uv4* __restrict__ bh,
                                                const int* __restrict__ cnt,
                                                const unsigned* __restrict__ ell,
                                                uv4* __restrict__ oh) {
    int wid = (blockIdx.x * 256 + threadIdx.x) >> 6;
    int lane = threadIdx.x & 63;
    int fl = lane & 7;
    long o = (long)wid * 8 + fl;
    uv4 bb = bh[o];                   // prefetched; in flight across the loop
    float a[8];
    float ws;
    gather_core(xh, cnt, ell, wid, lane, a, ws);
    if ((lane >> 3) == 0) {
        float s5 = 0.5f / fmaxf(ws, 1e-12f);   // 0.5 * inv_rowsum
        float2 f;
        uv4 r;
        f = uph(bb.x); r.x = pkh(s5 * a[0] + 0.5f * f.x, s5 * a[1] + 0.5f * f.y);
        f = uph(bb.y); r.y = pkh(s5 * a[2] + 0.5f * f.x, s5 * a[3] + 0.5f * f.y);
        f = uph(bb.z); r.z = pkh(s5 * a[4] + 0.5f * f.x, s5 * a[5] + 0.5f * f.y);
        f = uph(bb.w); r.w = pkh(s5 * a[6] + 0.5f * f.x, s5 * a[7] + 0.5f * f.y);
        oh[o] = r;
    }
}

// extrapolating finisher: out = agg/rowsum + b - x_k  (= 2*step - x_k).
// Ahat row-stochastic (to fp32 precision) => ones-vector is an exact
// lambda=0.5 eigenvector of M; (2M-I) zeroes that mode, leaving only the
// ~0.14^k random-graph bulk. Reads fp16 bh, writes fp32 d_out.
__global__ __launch_bounds__(256) void gather_xfinal(const uv4* __restrict__ xh,
                                                     const uv4* __restrict__ bh,
                                                     const int* __restrict__ cnt,
                                                     const unsigned* __restrict__ ell,
                                                     float4* __restrict__ of) {
    int wid = (blockIdx.x * 256 + threadIdx.x) >> 6;
    int lane = threadIdx.x & 63;
    int fl = lane & 7;
    float a[8];
    float ws;
    gather_core(xh, cnt, ell, wid, lane, a, ws);
    if ((lane >> 3) == 0) {
        float inv = 1.0f / fmaxf(ws, 1e-12f);
        long oh16 = (long)wid * 8 + fl;
        uv4 xo = xh[oh16];                 // own row, features 8*fl..8*fl+7
        uv4 bb = bh[oh16];
        float2 x01 = uph(xo.x), x23 = uph(xo.y), x45 = uph(xo.z), x67 = uph(xo.w);
        float2 b01 = uph(bb.x), b23 = uph(bb.y), b45 = uph(bb.z), b67 = uph(bb.w);
        long o = (long)wid * 16 + 2 * fl;  // float4 index
        float4 r0, r1;
        r0.x = inv * a[0] + b01.x - x01.x;
        r0.y = inv * a[1] + b01.y - x01.y;
        r0.z = inv * a[2] + b23.x - x23.x;
        r0.w = inv * a[3] + b23.y - x23.y;
        r1.x = inv * a[4] + b45.x - x45.x;
        r1.y = inv * a[5] + b45.y - x45.y;
        r1.z = inv * a[6] + b67.x - x67.x;
        r1.w = inv * a[7] + b67.y - x67.y;
        of[o] = r0;
        of[o + 1] = r1;
    }
}

// ---------------- launch ----------------

extern "C" void kernel_launch(void* const* d_in, const int* in_sizes, int n_in,
                              void* d_out, int out_size, void* d_ws, size_t ws_size,
                              hipStream_t stream) {
    // x_in (d_in[0]) unused: the fixed point is unique; x0 = b starts ~10x closer.
    const float*  e   = (const float*)d_in[1];
    const float4* b4  = (const float4*)d_in[2];
    const int*    src = (const int*)d_in[3];
    const int*    dst = (const int*)d_in[4];

    // ---- workspace layout (256B-aligned) ----
    char* ws = (char*)d_ws;
    size_t off = 0;
    int*      cnt = (int*)(ws + off);      off += ((size_t)NN * 4 + 255) & ~(size_t)255;
    unsigned* ell = (unsigned*)(ws + off); off += ((size_t)NN * CAP * 4 + 255) & ~(size_t)255;
    uv4*      xh0 = (uv4*)(ws + off);      off += ((size_t)NF * 2 + 255) & ~(size_t)255;
    uv4*      xh1 = (uv4*)(ws + off);      off += ((size_t)NF * 2 + 255) & ~(size_t)255;
    uv4*      bh  = (uv4*)(ws + off);      off += ((size_t)NF * 2 + 255) & ~(size_t)255;

    // ---- build (once per launch): 2 dispatches ----
    zero_cvt<<<CVTB + ZB, 256, 0, stream>>>(cnt, b4, (uv2*)bh);
    build_ell<<<NE / 256, 256, 0, stream>>>(e, src, dst, cnt, ell);

    // ---- NH fp16 apps (x0 = bh) + extrapolating fp32 finisher ----
    const int gblocks = NN / 4;   // one wave per node, 4 waves/block (exact)
    gather_h<<<gblocks, 256, 0, stream>>>(bh, bh, cnt, ell, xh0);
    gather_h<<<gblocks, 256, 0, stream>>>(xh0, bh, cnt, ell, xh1);
    gather_h<<<gblocks, 256, 0, stream>>>(xh1, bh, cnt, ell, xh0);
    gather_xfinal<<<gblocks, 256, 0, stream>>>(xh0, bh, cnt, ell, (float4*)d_out);
}

// Round 3
// 183.234 us; speedup vs baseline: 1.1997x; 1.1322x over previous
//
#include <hip/hip_runtime.h>
#include <hip/hip_fp16.h>

#define NN 50000
#define NE 800000
#define NF (NN * 64)
#define CAP 64                  // ELL capacity; deg ~ Poisson(16), P(deg>64) ~ 0
#define NH 3                    // fp16 apps; + 1 extrapolating fp32 finisher

typedef unsigned uv2 __attribute__((ext_vector_type(2)));
typedef unsigned uv4 __attribute__((ext_vector_type(4)));

static __device__ __forceinline__ float2 uph(unsigned u) {
    __half2 h = *(reinterpret_cast<__half2*>(&u));
    return __half22float2(h);
}
static __device__ __forceinline__ unsigned pkh(float a, float b) {
    __half2 h = __floats2half2_rn(a, b);
    return *(reinterpret_cast<unsigned*>(&h));
}
// pack (src:16 | fp16 weight:16); weight is positive (raw e in [0,1))
static __device__ __forceinline__ unsigned pack_sw(unsigned s, float w) {
    return ((unsigned)__half_as_ushort(__float2half_rn(w)) << 16) | s;
}
static __device__ __forceinline__ float unpack_w(unsigned u) {
    return __half2float(__ushort_as_half((unsigned short)(u >> 16)));
}

// ---------------- build ----------------

// fused: blocks [0, CVTB) cast b fp32->fp16 (streaming); blocks [CVTB, ...)
// zero the per-node counters.
#define CVTB (NF / 4 / 256)          // 3125 (exact)
#define ZB ((NN + 255) / 256)        // 196
__global__ __launch_bounds__(256) void zero_cvt(int* __restrict__ cnt,
                                                const float4* __restrict__ b4,
                                                uv2* __restrict__ bh) {
    if (blockIdx.x < CVTB) {
        int i = blockIdx.x * 256 + threadIdx.x;
        float4 v = b4[i];
        uv2 r;
        r.x = pkh(v.x, v.y);
        r.y = pkh(v.z, v.w);
        bh[i] = r;
    } else {
        int i = (blockIdx.x - CVTB) * 256 + threadIdx.x;
        if (i < NN) cnt[i] = 0;
    }
}

// single-pass ELL build with RAW fp16 weights (normalization happens on the
// fly in the gathers). Bounce-bound floor ~46us; r5/r11 locality variants
// both failed to beat this, coop-fusion (r14) was 6x worse.
__global__ __launch_bounds__(256) void build_ell(const float* __restrict__ e,
                                                 const int* __restrict__ src,
                                                 const int* __restrict__ dst,
                                                 int* __restrict__ cnt,
                                                 unsigned* __restrict__ ell) {
    int i = blockIdx.x * 256 + threadIdx.x;
    if (i < NE) {
        int d = dst[i];
        int r = atomicAdd(&cnt[d], 1);
        if (r < CAP)
            ell[d * CAP + r] = pack_sw((unsigned)src[i], e[i]);
    }
}

// ---------------- hot loop ----------------
// Decomposition: wave = 8 nodes x 8 feature-lanes.
// Each 8-lane group owns ONE node; each lane owns 8 features (one uv4 of the
// fp16 row) and accumulates them privately across ALL the node's edges.
//  - ZERO cross-lane ops: the old 1-node-per-wave layout spent ~31 wave-wide
//    ds_bpermutes per node (4 distribution + 27 butterfly) ~ 15us/gather of
//    DS-pipe serialization, plus a serial 3-round reduce chain per wave and
//    an 8/64-lane epilogue. All gone; ws (row sum) is computed redundantly
//    per lane for free.
//  - Edge words: one uv4 load = 4 packed edges, same address across the 8
//    group lanes (1 request); gives 4 independent x-row gathers in flight.
//  - Epilogue: all 64 lanes store; the wave's 8 consecutive nodes make the
//    output a contiguous, fully-coalesced 1KB (fp16) / 2KB (fp32) store.
// FP note: per-node accumulation is sequential ascending-j; fp32 accumulation
// either way, ~1e-6 perturbation vs the butterfly order.
//
// r2 bug (fixed): grid was NN/8/4 = 1562 blocks, but a 128-thread block
// covers 2 waves x 8 = 16 nodes -> need NN/16 = 3125. Half the nodes were
// never computed (absmax 0.258 = memset zeros).

static __device__ __forceinline__ void acc8(float w, uv4 u,
                                            float* __restrict__ a, float& ws) {
    float2 f;
    f = uph(u.x); a[0] += w * f.x; a[1] += w * f.y;
    f = uph(u.y); a[2] += w * f.x; a[3] += w * f.y;
    f = uph(u.z); a[4] += w * f.x; a[5] += w * f.y;
    f = uph(u.w); a[6] += w * f.x; a[7] += w * f.y;
    ws += w;
}

// per-lane gather core; node is group-uniform (8 lanes), fl = lane&7
static __device__ __forceinline__ void gather_core(
        const uv4* __restrict__ xh, const int* __restrict__ cnt,
        const uv4* __restrict__ ell4, int node, int fl,
        float* __restrict__ a, float& ws) {
    int deg = cnt[node];
    deg = deg < CAP ? deg : CAP;
    long eb = (long)node * (CAP / 4);   // uv4 index of this node's ELL row
#pragma unroll
    for (int k = 0; k < 8; ++k) a[k] = 0.0f;
    ws = 0.0f;
    // group-coherent trip count: ceil(deg/4); divergence cost = max over the
    // wave's 8 nodes (~6 trips for Poisson(16)) via exec-mask.
    for (int t = 0; 4 * t < deg; ++t) {
        uv4 pp = ell4[eb + t];          // 4 edges, broadcast across the group
        int rem = deg - 4 * t;
        float w0 = unpack_w(pp.x);
        float w1 = rem > 1 ? unpack_w(pp.y) : 0.0f;
        float w2 = rem > 2 ? unpack_w(pp.z) : 0.0f;
        float w3 = rem > 3 ? unpack_w(pp.w) : 0.0f;
        int s0 = (int)(pp.x & 0xFFFFu);
        int s1 = rem > 1 ? (int)(pp.y & 0xFFFFu) : 0;   // dummy row 0, w=0
        int s2 = rem > 2 ? (int)(pp.z & 0xFFFFu) : 0;
        int s3 = rem > 3 ? (int)(pp.w & 0xFFFFu) : 0;
        // 4 independent 128B row-gathers in flight per group
        uv4 u0 = xh[s0 * 8 + fl];
        uv4 u1 = xh[s1 * 8 + fl];
        uv4 u2 = xh[s2 * 8 + fl];
        uv4 u3 = xh[s3 * 8 + fl];
        acc8(w0, u0, a, ws);
        acc8(w1, u1, a, ws);
        acc8(w2, u2, a, ws);
        acc8(w3, u3, a, ws);
    }
}

// grid: 3125 blocks x 128 threads = 6250 waves = 50000 nodes (exact)
__global__ __launch_bounds__(128) void gather_h(const uv4* __restrict__ xh,
                                                const uv4* __restrict__ bh,
                                                const int* __restrict__ cnt,
                                                const uv4* __restrict__ ell4,
                                                uv4* __restrict__ oh) {
    int wv = (blockIdx.x * 128 + threadIdx.x) >> 6;
    int lane = threadIdx.x & 63;
    int node = wv * 8 + (lane >> 3);
    int fl = lane & 7;
    long o = (long)node * 8 + fl;
    uv4 bb = bh[o];                   // prefetched; in flight across the loop
    float a[8];
    float ws;
    gather_core(xh, cnt, ell4, node, fl, a, ws);
    float s5 = 0.5f / fmaxf(ws, 1e-12f);   // 0.5 * inv_rowsum
    float2 f;
    uv4 r;
    f = uph(bb.x); r.x = pkh(s5 * a[0] + 0.5f * f.x, s5 * a[1] + 0.5f * f.y);
    f = uph(bb.y); r.y = pkh(s5 * a[2] + 0.5f * f.x, s5 * a[3] + 0.5f * f.y);
    f = uph(bb.z); r.z = pkh(s5 * a[4] + 0.5f * f.x, s5 * a[5] + 0.5f * f.y);
    f = uph(bb.w); r.w = pkh(s5 * a[6] + 0.5f * f.x, s5 * a[7] + 0.5f * f.y);
    oh[o] = r;
}

// extrapolating finisher: out = agg/rowsum + b - x_k  (= 2*step - x_k).
// Ahat row-stochastic (to fp32 precision) => ones-vector is an exact
// lambda=0.5 eigenvector of M; (2M-I) zeroes that mode, leaving only the
// ~0.14^k random-graph bulk. Reads fp16 bh, writes fp32 d_out.
__global__ __launch_bounds__(128) void gather_xfinal(const uv4* __restrict__ xh,
                                                     const uv4* __restrict__ bh,
                                                     const int* __restrict__ cnt,
                                                     const uv4* __restrict__ ell4,
                                                     float4* __restrict__ of) {
    int wv = (blockIdx.x * 128 + threadIdx.x) >> 6;
    int lane = threadIdx.x & 63;
    int node = wv * 8 + (lane >> 3);
    int fl = lane & 7;
    long oh16 = (long)node * 8 + fl;
    uv4 xo = xh[oh16];                 // own row, features 8*fl..8*fl+7
    uv4 bb = bh[oh16];
    float a[8];
    float ws;
    gather_core(xh, cnt, ell4, node, fl, a, ws);
    float inv = 1.0f / fmaxf(ws, 1e-12f);
    float2 x01 = uph(xo.x), x23 = uph(xo.y), x45 = uph(xo.z), x67 = uph(xo.w);
    float2 b01 = uph(bb.x), b23 = uph(bb.y), b45 = uph(bb.z), b67 = uph(bb.w);
    long o = (long)node * 16 + 2 * fl;  // float4 index
    float4 r0, r1;
    r0.x = inv * a[0] + b01.x - x01.x;
    r0.y = inv * a[1] + b01.y - x01.y;
    r0.z = inv * a[2] + b23.x - x23.x;
    r0.w = inv * a[3] + b23.y - x23.y;
    r1.x = inv * a[4] + b45.x - x45.x;
    r1.y = inv * a[5] + b45.y - x45.y;
    r1.z = inv * a[6] + b67.x - x67.x;
    r1.w = inv * a[7] + b67.y - x67.y;
    of[o] = r0;
    of[o + 1] = r1;
}

// ---------------- launch ----------------

extern "C" void kernel_launch(void* const* d_in, const int* in_sizes, int n_in,
                              void* d_out, int out_size, void* d_ws, size_t ws_size,
                              hipStream_t stream) {
    // x_in (d_in[0]) unused: the fixed point is unique; x0 = b starts ~10x closer.
    const float*  e   = (const float*)d_in[1];
    const float4* b4  = (const float4*)d_in[2];
    const int*    src = (const int*)d_in[3];
    const int*    dst = (const int*)d_in[4];

    // ---- workspace layout (256B-aligned) ----
    char* ws = (char*)d_ws;
    size_t off = 0;
    int*      cnt = (int*)(ws + off);      off += ((size_t)NN * 4 + 255) & ~(size_t)255;
    unsigned* ell = (unsigned*)(ws + off); off += ((size_t)NN * CAP * 4 + 255) & ~(size_t)255;
    uv4*      xh0 = (uv4*)(ws + off);      off += ((size_t)NF * 2 + 255) & ~(size_t)255;
    uv4*      xh1 = (uv4*)(ws + off);      off += ((size_t)NF * 2 + 255) & ~(size_t)255;
    uv4*      bh  = (uv4*)(ws + off);      off += ((size_t)NF * 2 + 255) & ~(size_t)255;

    // ---- build (once per launch): 2 dispatches ----
    zero_cvt<<<CVTB + ZB, 256, 0, stream>>>(cnt, b4, (uv2*)bh);
    build_ell<<<NE / 256, 256, 0, stream>>>(e, src, dst, cnt, ell);

    // ---- NH fp16 apps (x0 = bh) + extrapolating fp32 finisher ----
    const int gblocks = NN / 16;   // 8 nodes/wave, 2 waves/block -> 16 nodes/block (exact: 3125)
    gather_h<<<gblocks, 128, 0, stream>>>(bh, bh, cnt, (const uv4*)ell, xh0);
    gather_h<<<gblocks, 128, 0, stream>>>(xh0, bh, cnt, (const uv4*)ell, xh1);
    gather_h<<<gblocks, 128, 0, stream>>>(xh1, bh, cnt, (const uv4*)ell, xh0);
    gather_xfinal<<<gblocks, 128, 0, stream>>>(xh0, bh, cnt, (const uv4*)ell, (float4*)d_out);
}